// Round 6
// baseline (187.101 us; speedup 1.0000x reference)
//
#include <hip/hip_runtime.h>
#include <hip/hip_bf16.h>
#include <math.h>

#define NV 131072
#define KOFF 27
#define ZROWS 64  // zero-pad region rows (spread hot line)

typedef __attribute__((ext_vector_type(8))) short short8;
typedef __attribute__((ext_vector_type(4))) float floatx4;

__device__ inline float silu_f(float x) { return x / (1.0f + expf(-x)); }

// ---------- fused pre kernel: role-partitioned grid ----------
// [0,512): transpose nbr -> nbr_t as BYTE offsets (row*128), zero-region remap
// [512,2560): LN1+silu -> h0
// [2560,2992): W1/W2 -> bf16 transposed
// [2992,3120): FiLM
// [3120,3122): zero-pad regions of h0/h2
__global__ void pre_kernel(const float* __restrict__ feats, const float* __restrict__ emb,
                           const float* __restrict__ gamma, const float* __restrict__ beta,
                           const float* __restrict__ W1, const float* __restrict__ W2,
                           const float* __restrict__ emb_W, const float* __restrict__ emb_b,
                           const int* __restrict__ nbr,
                           __hip_bfloat16* __restrict__ W1t, __hip_bfloat16* __restrict__ W2t,
                           float* __restrict__ ss, __hip_bfloat16* __restrict__ h0,
                           __hip_bfloat16* __restrict__ h2, unsigned int* __restrict__ nbr_t) {
    int gid = blockIdx.x, tid = threadIdx.x;
    if (gid < 512) {
        __shared__ int s[256 * KOFF];
        int r0 = gid * 256;
        for (int i = tid; i < 256 * KOFF; i += 256) s[i] = nbr[r0 * KOFF + i];
        __syncthreads();
        int r = r0 + tid;
        int zr = NV + ((r >> 7) & (ZROWS - 1));  // per-conv-block zero row
#pragma unroll
        for (int k = 0; k < KOFF; ++k) {
            int v = s[tid * KOFF + k];
            nbr_t[k * NV + r] = (unsigned int)(((v == NV) ? zr : v) << 7);  // byte offset
        }
    } else if (gid < 2560) {
        int row = (gid - 512) * 4 + (tid >> 6);
        int c = tid & 63;
        float x = feats[row * 64 + c];
        float s = x;
#pragma unroll
        for (int m = 1; m < 64; m <<= 1) s += __shfl_xor(s, m);
        float mu = s * (1.0f / 64.0f);
        float d = x - mu, q = d * d;
#pragma unroll
        for (int m = 1; m < 64; m <<= 1) q += __shfl_xor(q, m);
        float inv = rsqrtf(q * (1.0f / 64.0f) + 1e-6f);
        h0[row * 64 + c] = __float2bfloat16(silu_f(d * inv * gamma[c] + beta[c]));
    } else if (gid < 2992) {
        int t = (gid - 2560) * 256 + tid;  // < 110592
        int k = t >> 12, co = (t >> 6) & 63, ci = t & 63;
        int src = k * 4096 + ci * 64 + co;
        W1t[t] = __float2bfloat16(W1[src]);
        W2t[t] = __float2bfloat16(W2[src]);
    } else if (gid < 3120) {
        int wv = (gid - 2992) * 4 + (tid >> 6);  // 0..511
        int lane = tid & 63;
        int b = wv >> 7, c = wv & 127;
        float acc = 0.0f;
#pragma unroll
        for (int i = 0; i < 8; ++i) {
            int e = i * 64 + lane;
            acc += silu_f(emb[b * 512 + e]) * emb_W[e * 128 + c];
        }
#pragma unroll
        for (int m = 1; m < 64; m <<= 1) acc += __shfl_xor(acc, m);
        if (lane == 0) ss[wv] = acc + emb_b[c];
    } else {
        int t = (gid - 3120) * 256 + tid;
        if (t < ZROWS * 8) {
            short8 z = (short8){0, 0, 0, 0, 0, 0, 0, 0};
            ((short8*)h0)[NV * 8 + t] = z;
            ((short8*)h2)[NV * 8 + t] = z;
        }
    }
}

// ---------- gather-MFMA sparse conv; unrolled x2, byte-offset rulebook ----------
// 32 rows/wave, 128 rows/block, 1024 blocks
// XCD swizzle: HW round-robins blockIdx%8 across XCDs -> give each XCD a
// CONTIGUOUS 128-block (16384-row, ~2MB) span so neighbor gathers share L2.
template <int EPI>
__global__ __launch_bounds__(256, 4) void conv_kernel(
    const __hip_bfloat16* __restrict__ hsrc,   // [NV+ZROWS, 64] (rows >= NV zero)
    const __hip_bfloat16* __restrict__ Wt,     // [27, 64, 64] (k, cout, cin) bf16
    const unsigned int* __restrict__ nbr_t,    // [27, NV] byte offsets (row*128)
    const int* __restrict__ batch_idx,         // [NV]
    const float* __restrict__ ss,              // [4, 128]
    const float* __restrict__ bias,            // [64]
    const float* __restrict__ feats,           // [NV, 64] (EPI=1)
    __hip_bfloat16* __restrict__ dst_bf, float* __restrict__ dst_f32) {
    __shared__ short sB[2][4096];  // two 8KB swizzled B buffers
    __shared__ float s_ss[512];

    int tid = threadIdx.x, lane = tid & 63, wave = tid >> 6;
    int l15 = lane & 15, quad = lane >> 4;
    int lb = (blockIdx.x & 7) * 128 + (blockIdx.x >> 3);  // XCD-contiguous logical block
    int roww = lb * 128 + wave * 32;

    if (EPI == 0) {
        s_ss[tid] = ss[tid];
        s_ss[tid + 256] = ss[tid + 256];
    }

    const char* hb = (const char*)hsrc;
    const short8* w8 = (const short8*)Wt;
    char* sbase = (char*)sB;

    // staging positions (XOR swizzle: chunk c -> row*8 + ((c&7)^(row&7)))
    int c0 = tid, c1 = tid + 256;
    int pw0 = (((c0 >> 3) * 8) + ((c0 & 7) ^ ((c0 >> 3) & 7))) * 16;
    int pw1 = (((c1 >> 3) * 8) + ((c1 & 7) ^ ((c1 >> 3) & 7))) * 16;
    // read vaddrs: byte = l15*128 + ((ks*4+quad)^(l15&7))*16  (+ n*2048 + buf*8192 imm)
    int e7 = l15 & 7;
    int va0 = l15 * 128 + ((quad ^ e7) & 7) * 16;
    int va1 = l15 * 128 + (((4 | quad) ^ e7) & 7) * 16;

    const unsigned int* np = nbr_t + roww + l15;
    unsigned int qoff = (unsigned int)(quad * 16);

    // prologue: idx(0),(1); A(0); B(0)->LDS; B(1)->regs
    unsigned int jc0 = np[0], jc1 = np[16];
    unsigned int jn0 = np[NV], jn1 = np[NV + 16];
    *(short8*)(sbase + pw0) = w8[c0];
    *(short8*)(sbase + pw1) = w8[c1];
    short8 Br0 = w8[512 + c0], Br1 = w8[512 + c1];
    unsigned int po0 = jc0 + qoff, po1 = jc1 + qoff;
    short8 ac00 = *(const short8*)(hb + po0);
    short8 ac01 = *(const short8*)(hb + po0 + 64);
    short8 ac10 = *(const short8*)(hb + po1);
    short8 ac11 = *(const short8*)(hb + po1 + 64);

    floatx4 acc[2][4];
#pragma unroll
    for (int m = 0; m < 2; ++m)
#pragma unroll
        for (int n = 0; n < 4; ++n) acc[m][n] = (floatx4){0.f, 0.f, 0.f, 0.f};

    __asm__ __volatile__("s_waitcnt lgkmcnt(0)" ::: "memory");
    __builtin_amdgcn_s_barrier();

#define CITER(K, CURB, OTHB)                                                              \
    {                                                                                     \
        int kp2 = ((K) + 2 < KOFF) ? (K) + 2 : KOFF - 1;                                  \
        short8 Bn0 = w8[kp2 * 512 + c0];                                                  \
        short8 Bn1 = w8[kp2 * 512 + c1];                                                  \
        unsigned int j20 = np[(size_t)kp2 * NV];                                          \
        unsigned int j21 = np[(size_t)kp2 * NV + 16];                                     \
        unsigned int o0 = jn0 + qoff, o1 = jn1 + qoff;                                    \
        short8 an00 = *(const short8*)(hb + o0);                                          \
        short8 an01 = *(const short8*)(hb + o0 + 64);                                     \
        short8 an10 = *(const short8*)(hb + o1);                                          \
        short8 an11 = *(const short8*)(hb + o1 + 64);                                     \
        short8 bf00 = *(const short8*)(sbase + (CURB) + va0 + 0 * 2048);                  \
        short8 bf01 = *(const short8*)(sbase + (CURB) + va0 + 1 * 2048);                  \
        short8 bf02 = *(const short8*)(sbase + (CURB) + va0 + 2 * 2048);                  \
        short8 bf03 = *(const short8*)(sbase + (CURB) + va0 + 3 * 2048);                  \
        short8 bf10 = *(const short8*)(sbase + (CURB) + va1 + 0 * 2048);                  \
        short8 bf11 = *(const short8*)(sbase + (CURB) + va1 + 1 * 2048);                  \
        short8 bf12 = *(const short8*)(sbase + (CURB) + va1 + 2 * 2048);                  \
        short8 bf13 = *(const short8*)(sbase + (CURB) + va1 + 3 * 2048);                  \
        *(short8*)(sbase + (OTHB) + pw0) = Br0;                                           \
        *(short8*)(sbase + (OTHB) + pw1) = Br1;                                           \
        acc[0][0] = __builtin_amdgcn_mfma_f32_16x16x32_bf16(ac00, bf00, acc[0][0], 0, 0, 0); \
        acc[0][1] = __builtin_amdgcn_mfma_f32_16x16x32_bf16(ac00, bf01, acc[0][1], 0, 0, 0); \
        acc[0][2] = __builtin_amdgcn_mfma_f32_16x16x32_bf16(ac00, bf02, acc[0][2], 0, 0, 0); \
        acc[0][3] = __builtin_amdgcn_mfma_f32_16x16x32_bf16(ac00, bf03, acc[0][3], 0, 0, 0); \
        acc[1][0] = __builtin_amdgcn_mfma_f32_16x16x32_bf16(ac10, bf00, acc[1][0], 0, 0, 0); \
        acc[1][1] = __builtin_amdgcn_mfma_f32_16x16x32_bf16(ac10, bf01, acc[1][1], 0, 0, 0); \
        acc[1][2] = __builtin_amdgcn_mfma_f32_16x16x32_bf16(ac10, bf02, acc[1][2], 0, 0, 0); \
        acc[1][3] = __builtin_amdgcn_mfma_f32_16x16x32_bf16(ac10, bf03, acc[1][3], 0, 0, 0); \
        acc[0][0] = __builtin_amdgcn_mfma_f32_16x16x32_bf16(ac01, bf10, acc[0][0], 0, 0, 0); \
        acc[0][1] = __builtin_amdgcn_mfma_f32_16x16x32_bf16(ac01, bf11, acc[0][1], 0, 0, 0); \
        acc[0][2] = __builtin_amdgcn_mfma_f32_16x16x32_bf16(ac01, bf12, acc[0][2], 0, 0, 0); \
        acc[0][3] = __builtin_amdgcn_mfma_f32_16x16x32_bf16(ac01, bf13, acc[0][3], 0, 0, 0); \
        acc[1][0] = __builtin_amdgcn_mfma_f32_16x16x32_bf16(ac11, bf10, acc[1][0], 0, 0, 0); \
        acc[1][1] = __builtin_amdgcn_mfma_f32_16x16x32_bf16(ac11, bf11, acc[1][1], 0, 0, 0); \
        acc[1][2] = __builtin_amdgcn_mfma_f32_16x16x32_bf16(ac11, bf12, acc[1][2], 0, 0, 0); \
        acc[1][3] = __builtin_amdgcn_mfma_f32_16x16x32_bf16(ac11, bf13, acc[1][3], 0, 0, 0); \
        __asm__ __volatile__("s_waitcnt lgkmcnt(0)" ::: "memory");                        \
        __builtin_amdgcn_s_barrier();                                                     \
        ac00 = an00; ac01 = an01; ac10 = an10; ac11 = an11;                               \
        Br0 = Bn0; Br1 = Bn1; jn0 = j20; jn1 = j21;                                       \
    }

#pragma unroll 1
    for (int k = 0; k < KOFF - 1; k += 2) {
        CITER(k, 0, 8192);
        CITER(k + 1, 8192, 0);
    }
    CITER(KOFF - 1, 0, 8192);
#undef CITER

    // epilogue: C/D layout col = lane&15, row = quad*4 + r
    float bias_v[4];
#pragma unroll
    for (int n = 0; n < 4; ++n) bias_v[n] = bias[n * 16 + l15];

#pragma unroll
    for (int m = 0; m < 2; ++m) {
#pragma unroll
        for (int r = 0; r < 4; ++r) {
            int row = roww + m * 16 + quad * 4 + r;
            float v[4];
#pragma unroll
            for (int n = 0; n < 4; ++n) v[n] = acc[m][n][r] + bias_v[n];
            if (EPI == 0) {
                float s = v[0] + v[1] + v[2] + v[3];
                float q = v[0] * v[0] + v[1] * v[1] + v[2] * v[2] + v[3] * v[3];
#pragma unroll
                for (int msk = 1; msk < 16; msk <<= 1) {
                    s += __shfl_xor(s, msk);
                    q += __shfl_xor(q, msk);
                }
                float mu = s * (1.0f / 64.0f);
                float var = q * (1.0f / 64.0f) - mu * mu;
                float inv = rsqrtf(var + 1e-6f);
                int b = batch_idx[row];
                const float* sb = s_ss + b * 128;
#pragma unroll
                for (int n = 0; n < 4; ++n) {
                    float hn = (v[n] - mu) * inv;
                    float x = hn * (1.0f + sb[n * 16 + l15]) + sb[64 + n * 16 + l15];
                    dst_bf[row * 64 + n * 16 + l15] = __float2bfloat16(silu_f(x));
                }
            } else {
#pragma unroll
                for (int n = 0; n < 4; ++n)
                    dst_f32[row * 64 + n * 16 + l15] = v[n] + feats[row * 64 + n * 16 + l15];
            }
        }
    }
}

extern "C" void kernel_launch(void* const* d_in, const int* in_sizes, int n_in,
                              void* d_out, int out_size, void* d_ws, size_t ws_size,
                              hipStream_t stream) {
    (void)in_sizes; (void)n_in; (void)out_size; (void)ws_size;
    const float* feats = (const float*)d_in[0];
    const float* emb   = (const float*)d_in[1];
    const float* gamma = (const float*)d_in[2];
    const float* beta  = (const float*)d_in[3];
    const float* W1    = (const float*)d_in[4];
    const float* b1    = (const float*)d_in[5];
    const float* W2    = (const float*)d_in[6];
    const float* b2    = (const float*)d_in[7];
    const float* emb_W = (const float*)d_in[8];
    const float* emb_b = (const float*)d_in[9];
    const int* nbr     = (const int*)d_in[10];
    const int* bidx    = (const int*)d_in[11];
    float* out = (float*)d_out;

    const size_t HSZ = (size_t)(NV + ZROWS) * 64 * 2;  // bf16 buffer with zero region
    char* ws = (char*)d_ws;
    __hip_bfloat16* W1t = (__hip_bfloat16*)(ws);                  // 221184 B
    __hip_bfloat16* W2t = (__hip_bfloat16*)(ws + 221184);         // 221184 B
    float* ss           = (float*)(ws + 442368);                  // 2048 B
    __hip_bfloat16* h0  = (__hip_bfloat16*)(ws + 444416);
    __hip_bfloat16* h2  = (__hip_bfloat16*)(ws + 444416 + HSZ);
    unsigned int* nbr_t = (unsigned int*)(ws + 444416 + 2 * HSZ); // [27,NV] byte offsets

    pre_kernel<<<3122, 256, 0, stream>>>(feats, emb, gamma, beta, W1, W2, emb_W, emb_b,
                                         nbr, W1t, W2t, ss, h0, h2, nbr_t);
    conv_kernel<0><<<1024, 256, 0, stream>>>(h0, W1t, nbr_t, bidx, ss, b1, nullptr, h2, nullptr);
    conv_kernel<1><<<1024, 256, 0, stream>>>(h2, W2t, nbr_t, bidx, ss, b2, feats, nullptr, out);
}